// Round 1
// baseline (150.539 us; speedup 1.0000x reference)
//
#include <hip/hip_runtime.h>

#define N_SAMPLES 4096
#define DIM 2048
#define NUM_CLASSES 128
#define MARGIN 0.5f

// ---------------- ws layout (byte offsets) ----------------
// rows_sorted : N ints        @ 0
// cnt         : C ints        @ 16384
// start       : C ints        @ 16896
// meanR       : C*D floats    @ 32768
// meanT       : C*D floats    @ 32768 + 1048576
// total ~2.08 MB

// Kernel A: counting sort of targets by class, zero d_out.
__global__ void prep_kernel(const int* __restrict__ targets,
                            int* __restrict__ rows_sorted,
                            int* __restrict__ cnt,
                            int* __restrict__ start,
                            float* __restrict__ d_out) {
    __shared__ int s_cnt[NUM_CLASSES];
    __shared__ int s_off[NUM_CLASSES];
    const int tid = threadIdx.x;
    if (tid < NUM_CLASSES) s_cnt[tid] = 0;
    __syncthreads();
    for (int i = tid; i < N_SAMPLES; i += blockDim.x)
        atomicAdd(&s_cnt[targets[i]], 1);
    __syncthreads();
    if (tid == 0) {
        int run = 0;
        for (int c = 0; c < NUM_CLASSES; ++c) { s_off[c] = run; run += s_cnt[c]; }
        d_out[0] = 0.0f;
    }
    __syncthreads();
    if (tid < NUM_CLASSES) { cnt[tid] = s_cnt[tid]; start[tid] = s_off[tid]; }
    for (int i = tid; i < N_SAMPLES; i += blockDim.x) {
        const int c = targets[i];
        const int pos = atomicAdd(&s_off[c], 1);   // order within class irrelevant
        rows_sorted[pos] = i;
    }
}

// Kernel B: per-class means. grid (D/512, C, 2), block 256, float2 per thread.
// Each input element is read exactly once across the whole grid.
__global__ void mean_kernel(const float* __restrict__ x1,
                            const float* __restrict__ x2,
                            const int* __restrict__ rows_sorted,
                            const int* __restrict__ cnt,
                            const int* __restrict__ start,
                            float* __restrict__ meanR,
                            float* __restrict__ meanT) {
    const int c = blockIdx.y;
    const float* __restrict__ x = (blockIdx.z == 0) ? x1 : x2;
    float* __restrict__ mean    = (blockIdx.z == 0) ? meanR : meanT;
    const int col2 = blockIdx.x * blockDim.x + threadIdx.x;   // float2 index in [0,1024)
    const int n = cnt[c];
    const int s = start[c];
    const float2* __restrict__ xs = (const float2*)x;
    float ax = 0.0f, ay = 0.0f;
    for (int k = 0; k < n; ++k) {
        const int row = rows_sorted[s + k];
        const float2 v = xs[(size_t)row * (DIM / 2) + col2];
        ax += v.x; ay += v.y;
    }
    const float inv = 1.0f / (float)((n > 0) ? n : 1);
    float2 m; m.x = ax * inv; m.y = ay * inv;
    ((float2*)mean)[(size_t)c * (DIM / 2) + col2] = m;
}

__device__ __forceinline__ void accum_sq(float& acc, const float4& a, const float4& c) {
    float d;
    d = a.x - c.x; acc = fmaf(d, d, acc);
    d = a.y - c.y; acc = fmaf(d, d, acc);
    d = a.z - c.z; acc = fmaf(d, d, acc);
    d = a.w - c.w; acc = fmaf(d, d, acc);
}

__device__ __forceinline__ float wave_sum64(float v) {
#pragma unroll
    for (int m = 32; m >= 1; m >>= 1) v += __shfl_xor(v, m, 64);
    return v;
}

// Kernel D: class-pair distance + contrastive terms. One wave per 2a x 4b tile.
// waves = (128/2)*(128/4) = 2048 -> 512 blocks of 256 threads.
__global__ void loss_kernel(const float* __restrict__ meanR,
                            const float* __restrict__ meanT,
                            const int* __restrict__ cnt,
                            float* __restrict__ d_out) {
    const int gtid = blockIdx.x * blockDim.x + threadIdx.x;
    const int wid  = gtid >> 6;          // 0..2047
    const int lane = threadIdx.x & 63;
    const int a0 = (wid >> 5) * 2;       // a-tile: 2 classes
    const int b0 = (wid & 31) * 4;       // b-tile: 4 classes

    const float4* __restrict__ RA0 = (const float4*)(meanR + (size_t)(a0 + 0) * DIM);
    const float4* __restrict__ RA1 = (const float4*)(meanR + (size_t)(a0 + 1) * DIM);
    const float4* __restrict__ TA0 = (const float4*)(meanT + (size_t)(a0 + 0) * DIM);
    const float4* __restrict__ TA1 = (const float4*)(meanT + (size_t)(a0 + 1) * DIM);

    float acc1[2][4], acc2[2][4];
#pragma unroll
    for (int i = 0; i < 2; ++i)
#pragma unroll
        for (int j = 0; j < 4; ++j) { acc1[i][j] = 0.0f; acc2[i][j] = 0.0f; }

    const int ITERS = DIM / 4 / 64;      // 8
#pragma unroll 2
    for (int it = 0; it < ITERS; ++it) {
        const int d = lane + it * 64;    // float4 index
        const float4 ra0 = RA0[d], ra1 = RA1[d];
        const float4 ta0 = TA0[d], ta1 = TA1[d];
#pragma unroll
        for (int j = 0; j < 4; ++j) {
            const int b = b0 + j;
            const float4 rb = ((const float4*)(meanR + (size_t)b * DIM))[d];
            const float4 tb = ((const float4*)(meanT + (size_t)b * DIM))[d];
            float4 cb;
            cb.x = 0.5f * (rb.x + tb.x);
            cb.y = 0.5f * (rb.y + tb.y);
            cb.z = 0.5f * (rb.z + tb.z);
            cb.w = 0.5f * (rb.w + tb.w);
            accum_sq(acc1[0][j], ra0, cb);
            accum_sq(acc1[1][j], ra1, cb);
            accum_sq(acc2[0][j], ta0, cb);
            accum_sq(acc2[1][j], ta1, cb);
        }
    }

    // wave-wide reduction of all 16+16 accumulators
#pragma unroll
    for (int i = 0; i < 2; ++i)
#pragma unroll
        for (int j = 0; j < 4; ++j) {
            acc1[i][j] = wave_sum64(acc1[i][j]);
            acc2[i][j] = wave_sum64(acc2[i][j]);
        }

    if (lane == 0) {
        const float invN2 = 1.0f / ((float)N_SAMPLES * (float)N_SAMPLES);
        float total = 0.0f;
#pragma unroll
        for (int i = 0; i < 2; ++i) {
            const int a = a0 + i;
            const float ca = (float)cnt[a];
#pragma unroll
            for (int j = 0; j < 4; ++j) {
                const int b = b0 + j;
                const float w = ca * (float)cnt[b] * invN2;
                const float sq1 = fmaxf(acc1[i][j], 1e-12f);
                const float sq2 = fmaxf(acc2[i][j], 1e-12f);
                float t1, t2;
                if (a == b) {
                    t1 = sq1;             // label * dist^2  (dist^2 == clamped sq)
                    t2 = sq2;
                } else {
                    const float dd1 = sqrtf(sqrtf(sq1) + 1e-10f);
                    const float dd2 = sqrtf(sqrtf(sq2) + 1e-10f);
                    const float r1 = fmaxf(MARGIN - dd1, 0.0f);
                    const float r2 = fmaxf(MARGIN - dd2, 0.0f);
                    t1 = r1 * r1;
                    t2 = r2 * r2;
                }
                total += w * (t1 + t2);
            }
        }
        atomicAdd(d_out, total);
    }
}

extern "C" void kernel_launch(void* const* d_in, const int* in_sizes, int n_in,
                              void* d_out, int out_size, void* d_ws, size_t ws_size,
                              hipStream_t stream) {
    const float* modal1 = (const float*)d_in[0];
    const float* modal2 = (const float*)d_in[1];
    const int* targets  = (const int*)d_in[2];
    float* out = (float*)d_out;

    char* ws = (char*)d_ws;
    int*   rows_sorted = (int*)(ws + 0);
    int*   cnt         = (int*)(ws + 16384);
    int*   start       = (int*)(ws + 16896);
    float* meanR       = (float*)(ws + 32768);
    float* meanT       = (float*)(ws + 32768 + (size_t)NUM_CLASSES * DIM * 4);

    // 1. counting sort + zero output
    prep_kernel<<<1, 256, 0, stream>>>(targets, rows_sorted, cnt, start, out);

    // 2. per-class means (reads each input exactly once)
    dim3 gridB(DIM / 2 / 256, NUM_CLASSES, 2);   // (4, 128, 2)
    mean_kernel<<<gridB, 256, 0, stream>>>(modal1, modal2, rows_sorted, cnt, start,
                                           meanR, meanT);

    // 3. class-pair losses -> scalar
    const int waves = (NUM_CLASSES / 2) * (NUM_CLASSES / 4);  // 2048
    loss_kernel<<<waves / 4, 256, 0, stream>>>(meanR, meanT, cnt, out);
}

// Round 2
// 135.779 us; speedup vs baseline: 1.1087x; 1.1087x over previous
//
#include <hip/hip_runtime.h>

#define N_SAMPLES 4096
#define DIM 2048
#define NUM_CLASSES 128
#define MARGIN 0.5f

// ---------------- ws layout (byte offsets) ----------------
// rows_sorted : N ints        @ 0
// cnt         : C ints        @ 16384
// start       : C ints        @ 16896
// meanR       : C*D floats    @ 32768
// meanT       : C*D floats    @ 32768 + 1048576

// Kernel A: counting sort of targets by class, zero d_out.
// 1024 threads: 4 strided rounds over targets; wave-0 shuffle prefix scan.
__global__ __launch_bounds__(1024) void prep_kernel(
        const int* __restrict__ targets,
        int* __restrict__ rows_sorted,
        int* __restrict__ cnt,
        int* __restrict__ start,
        float* __restrict__ d_out, int out_size) {
    __shared__ int s_cnt[NUM_CLASSES];
    __shared__ int s_start[NUM_CLASSES];
    __shared__ int s_off[NUM_CLASSES];
    const int tid = threadIdx.x;
    if (tid < NUM_CLASSES) s_cnt[tid] = 0;
    for (int i = tid; i < out_size; i += blockDim.x) d_out[i] = 0.0f;
    __syncthreads();

    // histogram (4 rounds of 1024)
    int t0 = targets[tid];
    int t1 = targets[tid + 1024];
    int t2 = targets[tid + 2048];
    int t3 = targets[tid + 3072];
    atomicAdd(&s_cnt[t0], 1);
    atomicAdd(&s_cnt[t1], 1);
    atomicAdd(&s_cnt[t2], 1);
    atomicAdd(&s_cnt[t3], 1);
    __syncthreads();

    // exclusive prefix over 128 classes: wave 0 only, two 64-lane shuffle scans
    if (tid < 64) {
        const int lane = tid;
        const int a = s_cnt[lane];
        const int b = s_cnt[lane + 64];
        int xa = a;
#pragma unroll
        for (int m = 1; m < 64; m <<= 1) {
            int t = __shfl_up(xa, m, 64);
            if (lane >= m) xa += t;
        }
        const int totalA = __shfl(xa, 63, 64);
        int xb = b;
#pragma unroll
        for (int m = 1; m < 64; m <<= 1) {
            int t = __shfl_up(xb, m, 64);
            if (lane >= m) xb += t;
        }
        s_start[lane]      = xa - a;
        s_start[lane + 64] = totalA + xb - b;
    }
    __syncthreads();
    if (tid < NUM_CLASSES) {
        cnt[tid]   = s_cnt[tid];
        start[tid] = s_start[tid];
        s_off[tid] = s_start[tid];
    }
    __syncthreads();

    // scatter (order within class irrelevant)
    rows_sorted[atomicAdd(&s_off[t0], 1)] = tid;
    rows_sorted[atomicAdd(&s_off[t1], 1)] = tid + 1024;
    rows_sorted[atomicAdd(&s_off[t2], 1)] = tid + 2048;
    rows_sorted[atomicAdd(&s_off[t3], 1)] = tid + 3072;
}

// Kernel B: per-class means. grid (2, C, 2), block 256, float4/thread,
// row loop unrolled x4 for memory-level parallelism. Inputs read exactly once.
__global__ __launch_bounds__(256) void mean_kernel(
        const float* __restrict__ x1,
        const float* __restrict__ x2,
        const int* __restrict__ rows_sorted,
        const int* __restrict__ cnt,
        const int* __restrict__ start,
        float* __restrict__ meanR,
        float* __restrict__ meanT) {
    const int c = blockIdx.y;
    const float* __restrict__ x = (blockIdx.z == 0) ? x1 : x2;
    float* __restrict__ mean    = (blockIdx.z == 0) ? meanR : meanT;
    const int col = blockIdx.x * 256 + threadIdx.x;   // float4 index in [0,512)
    const int n = cnt[c];
    const int s = start[c];
    const float4* __restrict__ xs = (const float4*)x;

    float ax = 0.0f, ay = 0.0f, az = 0.0f, aw = 0.0f;
    int k = 0;
    for (; k + 4 <= n; k += 4) {
        const int r0 = rows_sorted[s + k + 0];
        const int r1 = rows_sorted[s + k + 1];
        const int r2 = rows_sorted[s + k + 2];
        const int r3 = rows_sorted[s + k + 3];
        const float4 v0 = xs[(size_t)r0 * (DIM / 4) + col];
        const float4 v1 = xs[(size_t)r1 * (DIM / 4) + col];
        const float4 v2 = xs[(size_t)r2 * (DIM / 4) + col];
        const float4 v3 = xs[(size_t)r3 * (DIM / 4) + col];
        ax += (v0.x + v1.x) + (v2.x + v3.x);
        ay += (v0.y + v1.y) + (v2.y + v3.y);
        az += (v0.z + v1.z) + (v2.z + v3.z);
        aw += (v0.w + v1.w) + (v2.w + v3.w);
    }
    for (; k < n; ++k) {
        const int r = rows_sorted[s + k];
        const float4 v = xs[(size_t)r * (DIM / 4) + col];
        ax += v.x; ay += v.y; az += v.z; aw += v.w;
    }
    const float inv = 1.0f / (float)((n > 0) ? n : 1);
    float4 m; m.x = ax * inv; m.y = ay * inv; m.z = az * inv; m.w = aw * inv;
    ((float4*)mean)[(size_t)c * (DIM / 4) + col] = m;
}

__device__ __forceinline__ void accum_sq(float& acc, const float4& a, const float4& c) {
    float d;
    d = a.x - c.x; acc = fmaf(d, d, acc);
    d = a.y - c.y; acc = fmaf(d, d, acc);
    d = a.z - c.z; acc = fmaf(d, d, acc);
    d = a.w - c.w; acc = fmaf(d, d, acc);
}

__device__ __forceinline__ float wave_sum64(float v) {
#pragma unroll
    for (int m = 32; m >= 1; m >>= 1) v += __shfl_xor(v, m, 64);
    return v;
}

// Kernel D: class-pair distance + contrastive terms. One wave per 2a x 4b tile.
__global__ __launch_bounds__(256) void loss_kernel(
        const float* __restrict__ meanR,
        const float* __restrict__ meanT,
        const int* __restrict__ cnt,
        float* __restrict__ d_out) {
    const int gtid = blockIdx.x * blockDim.x + threadIdx.x;
    const int wid  = gtid >> 6;          // 0..2047
    const int lane = threadIdx.x & 63;
    const int a0 = (wid >> 5) * 2;       // a-tile: 2 classes
    const int b0 = (wid & 31) * 4;       // b-tile: 4 classes

    const float4* __restrict__ RA0 = (const float4*)(meanR + (size_t)(a0 + 0) * DIM);
    const float4* __restrict__ RA1 = (const float4*)(meanR + (size_t)(a0 + 1) * DIM);
    const float4* __restrict__ TA0 = (const float4*)(meanT + (size_t)(a0 + 0) * DIM);
    const float4* __restrict__ TA1 = (const float4*)(meanT + (size_t)(a0 + 1) * DIM);

    float acc1[2][4], acc2[2][4];
#pragma unroll
    for (int i = 0; i < 2; ++i)
#pragma unroll
        for (int j = 0; j < 4; ++j) { acc1[i][j] = 0.0f; acc2[i][j] = 0.0f; }

    const int ITERS = DIM / 4 / 64;      // 8
#pragma unroll 2
    for (int it = 0; it < ITERS; ++it) {
        const int d = lane + it * 64;    // float4 index
        const float4 ra0 = RA0[d], ra1 = RA1[d];
        const float4 ta0 = TA0[d], ta1 = TA1[d];
#pragma unroll
        for (int j = 0; j < 4; ++j) {
            const int b = b0 + j;
            const float4 rb = ((const float4*)(meanR + (size_t)b * DIM))[d];
            const float4 tb = ((const float4*)(meanT + (size_t)b * DIM))[d];
            float4 cb;
            cb.x = 0.5f * (rb.x + tb.x);
            cb.y = 0.5f * (rb.y + tb.y);
            cb.z = 0.5f * (rb.z + tb.z);
            cb.w = 0.5f * (rb.w + tb.w);
            accum_sq(acc1[0][j], ra0, cb);
            accum_sq(acc1[1][j], ra1, cb);
            accum_sq(acc2[0][j], ta0, cb);
            accum_sq(acc2[1][j], ta1, cb);
        }
    }

#pragma unroll
    for (int i = 0; i < 2; ++i)
#pragma unroll
        for (int j = 0; j < 4; ++j) {
            acc1[i][j] = wave_sum64(acc1[i][j]);
            acc2[i][j] = wave_sum64(acc2[i][j]);
        }

    if (lane == 0) {
        const float invN2 = 1.0f / ((float)N_SAMPLES * (float)N_SAMPLES);
        float total = 0.0f;
#pragma unroll
        for (int i = 0; i < 2; ++i) {
            const int a = a0 + i;
            const float ca = (float)cnt[a];
#pragma unroll
            for (int j = 0; j < 4; ++j) {
                const int b = b0 + j;
                const float w = ca * (float)cnt[b] * invN2;
                const float sq1 = fmaxf(acc1[i][j], 1e-12f);
                const float sq2 = fmaxf(acc2[i][j], 1e-12f);
                float t1, t2;
                if (a == b) {
                    t1 = sq1;
                    t2 = sq2;
                } else {
                    const float dd1 = sqrtf(sqrtf(sq1) + 1e-10f);
                    const float dd2 = sqrtf(sqrtf(sq2) + 1e-10f);
                    const float r1 = fmaxf(MARGIN - dd1, 0.0f);
                    const float r2 = fmaxf(MARGIN - dd2, 0.0f);
                    t1 = r1 * r1;
                    t2 = r2 * r2;
                }
                total += w * (t1 + t2);
            }
        }
        atomicAdd(d_out, total);
    }
}

extern "C" void kernel_launch(void* const* d_in, const int* in_sizes, int n_in,
                              void* d_out, int out_size, void* d_ws, size_t ws_size,
                              hipStream_t stream) {
    const float* modal1 = (const float*)d_in[0];
    const float* modal2 = (const float*)d_in[1];
    const int* targets  = (const int*)d_in[2];
    float* out = (float*)d_out;

    char* ws = (char*)d_ws;
    int*   rows_sorted = (int*)(ws + 0);
    int*   cnt         = (int*)(ws + 16384);
    int*   start       = (int*)(ws + 16896);
    float* meanR       = (float*)(ws + 32768);
    float* meanT       = (float*)(ws + 32768 + (size_t)NUM_CLASSES * DIM * 4);

    // 1. counting sort + zero output
    prep_kernel<<<1, 1024, 0, stream>>>(targets, rows_sorted, cnt, start, out, out_size);

    // 2. per-class means (reads each input exactly once)
    dim3 gridB(2, NUM_CLASSES, 2);
    mean_kernel<<<gridB, 256, 0, stream>>>(modal1, modal2, rows_sorted, cnt, start,
                                           meanR, meanT);

    // 3. class-pair losses -> scalar
    const int waves = (NUM_CLASSES / 2) * (NUM_CLASSES / 4);  // 2048
    loss_kernel<<<waves / 4, 256, 0, stream>>>(meanR, meanT, cnt, out);
}

// Round 3
// 118.823 us; speedup vs baseline: 1.2669x; 1.1427x over previous
//
#include <hip/hip_runtime.h>

#define N_SAMPLES 4096
#define DIM 2048
#define NUM_CLASSES 128
#define MARGIN 0.5f

// ---------------- ws layout (byte offsets) ----------------
// cnt   : C ints        @ 0
// meanR : C*D floats    @ 1024
// meanT : C*D floats    @ 1024 + C*D*4

// Kernel 1: per-class means, self-contained (no pre-sort).
// grid (2, C, 2), block 256. Each block scans targets (16 KB, L2-hot),
// compacts its class's rows into LDS, then sums float4 columns with a
// 4-deep row unroll for MLP. Inputs read exactly once across the grid.
__global__ __launch_bounds__(256) void mean_kernel(
        const float* __restrict__ x1,
        const float* __restrict__ x2,
        const int* __restrict__ targets,
        int* __restrict__ cnt,
        float* __restrict__ meanR,
        float* __restrict__ meanT,
        float* __restrict__ d_out, int out_size) {
    __shared__ int s_rows[N_SAMPLES];
    __shared__ int s_n;
    const int tid = threadIdx.x;
    const int c = blockIdx.y;
    const float* __restrict__ x = (blockIdx.z == 0) ? x1 : x2;
    float* __restrict__ mean    = (blockIdx.z == 0) ? meanR : meanT;

    if (tid == 0) s_n = 0;
    if (blockIdx.x == 0 && blockIdx.y == 0 && blockIdx.z == 0) {
        for (int i = tid; i < out_size; i += 256) d_out[i] = 0.0f;  // loss runs after us
    }
    __syncthreads();

    // compact rows of class c (order irrelevant)
    const int4* __restrict__ t4 = (const int4*)targets;
    for (int i = tid; i < N_SAMPLES / 4; i += 256) {
        const int4 v = t4[i];
        const int base = i * 4;
        if (v.x == c) s_rows[atomicAdd(&s_n, 1)] = base;
        if (v.y == c) s_rows[atomicAdd(&s_n, 1)] = base + 1;
        if (v.z == c) s_rows[atomicAdd(&s_n, 1)] = base + 2;
        if (v.w == c) s_rows[atomicAdd(&s_n, 1)] = base + 3;
    }
    __syncthreads();
    const int n = s_n;

    const int col = blockIdx.x * 256 + tid;          // float4 index in [0,512)
    const float4* __restrict__ xs = (const float4*)x;
    float ax = 0.0f, ay = 0.0f, az = 0.0f, aw = 0.0f;
    int k = 0;
    for (; k + 4 <= n; k += 4) {
        const int r0 = s_rows[k + 0];                // LDS broadcast, free
        const int r1 = s_rows[k + 1];
        const int r2 = s_rows[k + 2];
        const int r3 = s_rows[k + 3];
        const float4 v0 = xs[(size_t)r0 * (DIM / 4) + col];
        const float4 v1 = xs[(size_t)r1 * (DIM / 4) + col];
        const float4 v2 = xs[(size_t)r2 * (DIM / 4) + col];
        const float4 v3 = xs[(size_t)r3 * (DIM / 4) + col];
        ax += (v0.x + v1.x) + (v2.x + v3.x);
        ay += (v0.y + v1.y) + (v2.y + v3.y);
        az += (v0.z + v1.z) + (v2.z + v3.z);
        aw += (v0.w + v1.w) + (v2.w + v3.w);
    }
    for (; k < n; ++k) {
        const int r = s_rows[k];
        const float4 v = xs[(size_t)r * (DIM / 4) + col];
        ax += v.x; ay += v.y; az += v.z; aw += v.w;
    }
    const float inv = 1.0f / (float)((n > 0) ? n : 1);
    float4 m; m.x = ax * inv; m.y = ay * inv; m.z = az * inv; m.w = aw * inv;
    ((float4*)mean)[(size_t)c * (DIM / 4) + col] = m;

    if (blockIdx.x == 0 && blockIdx.z == 0 && tid == 0) cnt[c] = n;
}

__device__ __forceinline__ void accum_sq(float& acc, const float4& a, const float4& c) {
    float d;
    d = a.x - c.x; acc = fmaf(d, d, acc);
    d = a.y - c.y; acc = fmaf(d, d, acc);
    d = a.z - c.z; acc = fmaf(d, d, acc);
    d = a.w - c.w; acc = fmaf(d, d, acc);
}

__device__ __forceinline__ float wave_sum64(float v) {
#pragma unroll
    for (int m = 32; m >= 1; m >>= 1) v += __shfl_xor(v, m, 64);
    return v;
}

// Kernel 2: class-pair distances + contrastive terms. One wave per 4a x 4b
// tile -> 1024 waves -> 256 blocks of 256. Logical traffic 134 MB, L2-resident.
__global__ __launch_bounds__(256) void loss_kernel(
        const float* __restrict__ meanR,
        const float* __restrict__ meanT,
        const int* __restrict__ cnt,
        float* __restrict__ d_out) {
    const int gtid = blockIdx.x * blockDim.x + threadIdx.x;
    const int wid  = gtid >> 6;          // 0..1023
    const int lane = threadIdx.x & 63;
    const int a0 = (wid >> 5) * 4;       // a-tile: 4 classes
    const int b0 = (wid & 31) * 4;       // b-tile: 4 classes

    float acc1[4][4], acc2[4][4];
#pragma unroll
    for (int i = 0; i < 4; ++i)
#pragma unroll
        for (int j = 0; j < 4; ++j) { acc1[i][j] = 0.0f; acc2[i][j] = 0.0f; }

    const int ITERS = DIM / 4 / 64;      // 8
#pragma unroll 2
    for (int it = 0; it < ITERS; ++it) {
        const int d = lane + it * 64;    // float4 index within a row
        float4 ra[4], ta[4];
#pragma unroll
        for (int i = 0; i < 4; ++i) {
            ra[i] = ((const float4*)(meanR + (size_t)(a0 + i) * DIM))[d];
            ta[i] = ((const float4*)(meanT + (size_t)(a0 + i) * DIM))[d];
        }
#pragma unroll
        for (int j = 0; j < 4; ++j) {
            const int b = b0 + j;
            const float4 rb = ((const float4*)(meanR + (size_t)b * DIM))[d];
            const float4 tb = ((const float4*)(meanT + (size_t)b * DIM))[d];
            float4 cb;
            cb.x = 0.5f * (rb.x + tb.x);
            cb.y = 0.5f * (rb.y + tb.y);
            cb.z = 0.5f * (rb.z + tb.z);
            cb.w = 0.5f * (rb.w + tb.w);
#pragma unroll
            for (int i = 0; i < 4; ++i) {
                accum_sq(acc1[i][j], ra[i], cb);
                accum_sq(acc2[i][j], ta[i], cb);
            }
        }
    }

#pragma unroll
    for (int i = 0; i < 4; ++i)
#pragma unroll
        for (int j = 0; j < 4; ++j) {
            acc1[i][j] = wave_sum64(acc1[i][j]);
            acc2[i][j] = wave_sum64(acc2[i][j]);
        }

    __shared__ float s_part[4];
    if (lane == 0) {
        const float invN2 = 1.0f / ((float)N_SAMPLES * (float)N_SAMPLES);
        float total = 0.0f;
#pragma unroll
        for (int i = 0; i < 4; ++i) {
            const int a = a0 + i;
            const float ca = (float)cnt[a];
#pragma unroll
            for (int j = 0; j < 4; ++j) {
                const int b = b0 + j;
                const float w = ca * (float)cnt[b] * invN2;
                const float sq1 = fmaxf(acc1[i][j], 1e-12f);
                const float sq2 = fmaxf(acc2[i][j], 1e-12f);
                float t1, t2;
                if (a == b) {
                    t1 = sq1;             // label==1: d2^2 == clamped sq
                    t2 = sq2;
                } else {
                    const float dd1 = sqrtf(sqrtf(sq1) + 1e-10f);
                    const float dd2 = sqrtf(sqrtf(sq2) + 1e-10f);
                    const float r1 = fmaxf(MARGIN - dd1, 0.0f);
                    const float r2 = fmaxf(MARGIN - dd2, 0.0f);
                    t1 = r1 * r1;
                    t2 = r2 * r2;
                }
                total += w * (t1 + t2);
            }
        }
        s_part[threadIdx.x >> 6] = total;
    }
    __syncthreads();
    if (threadIdx.x == 0)
        atomicAdd(d_out, (s_part[0] + s_part[1]) + (s_part[2] + s_part[3]));
}

extern "C" void kernel_launch(void* const* d_in, const int* in_sizes, int n_in,
                              void* d_out, int out_size, void* d_ws, size_t ws_size,
                              hipStream_t stream) {
    const float* modal1 = (const float*)d_in[0];
    const float* modal2 = (const float*)d_in[1];
    const int* targets  = (const int*)d_in[2];
    float* out = (float*)d_out;

    char* ws = (char*)d_ws;
    int*   cnt   = (int*)(ws + 0);
    float* meanR = (float*)(ws + 1024);
    float* meanT = (float*)(ws + 1024 + (size_t)NUM_CLASSES * DIM * 4);

    // 1. per-class means (self-gathering; also zeroes d_out, publishes cnt)
    dim3 gridB(2, NUM_CLASSES, 2);
    mean_kernel<<<gridB, 256, 0, stream>>>(modal1, modal2, targets, cnt,
                                           meanR, meanT, out, out_size);

    // 2. class-pair losses -> scalar (4x4 tiles, 1024 waves)
    const int waves = (NUM_CLASSES / 4) * (NUM_CLASSES / 4);  // 1024
    loss_kernel<<<waves / 4, 256, 0, stream>>>(meanR, meanT, cnt, out);
}